// Round 2
// baseline (356.106 us; speedup 1.0000x reference)
//
#include <hip/hip_runtime.h>

typedef unsigned short u16;
typedef unsigned int u32;
typedef __attribute__((ext_vector_type(8))) __bf16 bf16x8;
typedef __attribute__((ext_vector_type(8))) _Float16 f16x8;
typedef __attribute__((ext_vector_type(4))) float f32x4;

// ---------- helpers ----------
__device__ __forceinline__ float b2f(u16 b) {
    union { u32 u; float f; } v; v.u = ((u32)b) << 16; return v.f;
}
__device__ __forceinline__ u16 f2bf(float f) {
    union { float f; u32 u; } v; v.f = f;
    u32 u = v.u;
    return (u16)((u + 0x7fffu + ((u >> 16) & 1u)) >> 16);  // RNE
}
__device__ __forceinline__ u16 f2h(float f) {
    _Float16 h = (_Float16)f;   // RNE v_cvt_f16_f32
    return __builtin_bit_cast(u16, h);
}
__device__ __forceinline__ bf16x8 ldg8b(const u16* p) {
    uint4 v = *(const uint4*)p;
    return __builtin_bit_cast(bf16x8, v);
}
__device__ __forceinline__ f16x8 ldg8h(const u16* p) {
    uint4 v = *(const uint4*)p;
    return __builtin_bit_cast(f16x8, v);
}
__device__ __forceinline__ f32x4 mfma_bf(bf16x8 a, bf16x8 b, f32x4 c) {
    return __builtin_amdgcn_mfma_f32_16x16x32_bf16(a, b, c, 0, 0, 0);
}
__device__ __forceinline__ f32x4 mfma_h(f16x8 a, f16x8 b, f32x4 c) {
    return __builtin_amdgcn_mfma_f32_16x16x32_f16(a, b, c, 0, 0, 0);
}

// ---------- K0: hi/lo bf16 split of W, transposed: Wt[d][c] ----------
__global__ void k0_wt(const float* __restrict__ Wq,
                      u16* __restrict__ Wthi, u16* __restrict__ Wtlo) {
    int idx = blockIdx.x * 256 + threadIdx.x;   // 64 blocks -> 16384
    int c = idx >> 6, d = idx & 63;
    float w = Wq[idx];
    u16 hi = f2bf(w);
    float rem = w - b2f(hi);
    Wthi[d * 256 + c] = hi;
    Wtlo[d * 256 + c] = f2bf(rem);
}

// ---------- K1: Q[row][d] = sum_c F[row][c]*W[c][d], hi/lo split, fp16 out ----------
__global__ __launch_bounds__(256) void k1_query(
    const float* __restrict__ F, const u16* __restrict__ Wthi,
    const u16* __restrict__ Wtlo, u16* __restrict__ Qh) {
    const int t = threadIdx.x;
    const int w = t >> 6, L = t & 63, lane16 = L & 15, quad = L >> 4;
    const int R0 = blockIdx.x * 64;
    const int row = R0 + w * 16 + lane16;
    const f32x4 z4 = {0.f, 0.f, 0.f, 0.f};
    f32x4 acc[4] = {z4, z4, z4, z4};
    union U8 { bf16x8 v; u16 s[8]; };
#pragma unroll
    for (int ks = 0; ks < 8; ++ks) {
        const float* fp = F + (size_t)row * 256 + ks * 32 + quad * 8;
        float4 x0 = *(const float4*)fp;
        float4 x1 = *(const float4*)(fp + 4);
        float xs[8] = {x0.x, x0.y, x0.z, x0.w, x1.x, x1.y, x1.z, x1.w};
        U8 ahi, alo;
#pragma unroll
        for (int j = 0; j < 8; ++j) {
            u16 h = f2bf(xs[j]);
            ahi.s[j] = h;
            alo.s[j] = f2bf(xs[j] - b2f(h));
        }
#pragma unroll
        for (int nt = 0; nt < 4; ++nt) {
            const int off = (nt * 16 + lane16) * 256 + ks * 32 + quad * 8;
            bf16x8 bh = ldg8b(Wthi + off);
            bf16x8 bl = ldg8b(Wtlo + off);
            acc[nt] = mfma_bf(ahi.v, bh, acc[nt]);
            acc[nt] = mfma_bf(alo.v, bh, acc[nt]);
            acc[nt] = mfma_bf(ahi.v, bl, acc[nt]);
        }
    }
    const int orow = R0 + w * 16 + quad * 4;
#pragma unroll
    for (int nt = 0; nt < 4; ++nt)
#pragma unroll
        for (int r = 0; r < 4; ++r)
            Qh[(size_t)(orow + r) * 64 + nt * 16 + lane16] = f2h(acc[nt][r]);
}

// ---------- K2: inv_l[p] = 1 / sum_q exp(Q_p . Q_q)  (fp16 MFMA) ----------
__global__ __launch_bounds__(256) void k2_suminv(
    const u16* __restrict__ Q, float* __restrict__ inv_l) {
    const int t = threadIdx.x;
    const int w = t >> 6, L = t & 63, lane16 = L & 15, quad = L >> 4;
    const int bx = blockIdx.x;
    const int n = bx & 7, pb = bx >> 3;   // batch-per-XCD swizzle
    const int P0 = pb * 64;
    const u16* Qn = Q + (size_t)n * 4096 * 64;

    f16x8 ap[4][2];
#pragma unroll
    for (int st = 0; st < 4; ++st) {
        const u16* rp = Qn + (P0 + st * 16 + lane16) * 64 + quad * 8;
        ap[st][0] = ldg8h(rp);
        ap[st][1] = ldg8h(rp + 32);
    }
    float sums[4][4];
#pragma unroll
    for (int st = 0; st < 4; ++st)
#pragma unroll
        for (int r = 0; r < 4; ++r) sums[st][r] = 0.f;

    const f32x4 z4 = {0.f, 0.f, 0.f, 0.f};
    for (int s = 0; s < 32; ++s) {
        const int qc = w * 1024 + s * 32;
#pragma unroll
        for (int nt = 0; nt < 2; ++nt) {
            const u16* bp = Qn + (qc + nt * 16 + lane16) * 64 + quad * 8;
            f16x8 b0 = ldg8h(bp);
            f16x8 b1 = ldg8h(bp + 32);
#pragma unroll
            for (int st = 0; st < 4; ++st) {
                f32x4 z = z4;
                z = mfma_h(ap[st][0], b0, z);
                z = mfma_h(ap[st][1], b1, z);
                sums[st][0] += __expf(z[0]);
                sums[st][1] += __expf(z[1]);
                sums[st][2] += __expf(z[2]);
                sums[st][3] += __expf(z[3]);
            }
        }
    }
    __shared__ float red[4][64];
#pragma unroll
    for (int st = 0; st < 4; ++st)
#pragma unroll
        for (int r = 0; r < 4; ++r) {
            float v = sums[st][r];
            v += __shfl_xor(v, 1);
            v += __shfl_xor(v, 2);
            v += __shfl_xor(v, 4);
            v += __shfl_xor(v, 8);
            if (lane16 == 0) red[w][st * 16 + quad * 4 + r] = v;
        }
    __syncthreads();
    if (t < 64) {
        float tot = red[0][t] + red[1][t] + red[2][t] + red[3][t];
        inv_l[n * 4096 + P0 + t] = 1.0f / tot;
    }
}

// ---------- K3: Gt[n][c][p] = F[n][p][c] * inv_l[p]  (bf16 out) ----------
__global__ __launch_bounds__(256) void k3_gt(
    const float* __restrict__ F, const float* __restrict__ inv_l,
    u16* __restrict__ Gt) {
    const int t = threadIdx.x;
    const int bx = blockIdx.x;                  // 2048 = 8 * 64 * 4
    const int n = bx >> 8, pt = (bx >> 2) & 63, ct = bx & 3;
    const int p0 = pt * 64, c0 = ct * 64;
    __shared__ float tile[64][65];
    const float* Fn = F + (size_t)n * 4096 * 256;
#pragma unroll
    for (int k = 0; k < 16; ++k) {
        int idx = k * 256 + t;
        int r = idx >> 6, cc = idx & 63;
        tile[r][cc] = Fn[(size_t)(p0 + r) * 256 + c0 + cc];
    }
    __syncthreads();
    const float* il = inv_l + n * 4096 + p0;
    u16* Gn = Gt + (size_t)n * 256 * 4096;
#pragma unroll
    for (int k = 0; k < 16; ++k) {
        int idx = k * 256 + t;
        int rc = idx >> 6, pp = idx & 63;
        Gn[(size_t)(c0 + rc) * 4096 + p0 + pp] = f2bf(tile[pp][rc] * il[pp]);
    }
}

// ---------- K4: out tile (64 q x 256 ch), flash-style 2nd pass ----------
__global__ __launch_bounds__(256, 2) void k4_attn(
    const u16* __restrict__ Q, const u16* __restrict__ Gt,
    const float* __restrict__ mask, const float* __restrict__ ref,
    float* __restrict__ out) {
    const int t = threadIdx.x;
    const int w = t >> 6, L = t & 63, lane16 = L & 15, quad = L >> 4;
    const int bx = blockIdx.x;
    const int n = bx & 7, qb = bx >> 3;   // batch-per-XCD swizzle
    const int q0 = qb << 6;

    __shared__ u16 sQp[2][32 * 72];    // fp16 Q p-rows, 144 B rows
    __shared__ u16 sGt[2][256 * 40];   // bf16 Gt rows, 80 B rows
    __shared__ u16 sP[64 * 40];        // bf16 exp(S), 80 B rows

    const u16* Qn = Q + (size_t)n * 4096 * 64;
    const u16* Gtn = Gt + (size_t)n * 256 * 4096;

    // A-fragments of this wave's q-strip (constant over the p-loop)
    f16x8 aq0, aq1;
    {
        const u16* r0 = Qn + (q0 + w * 16 + lane16) * 64 + quad * 8;
        aq0 = ldg8h(r0);
        aq1 = ldg8h(r0 + 32);
    }

    // staging maps: Qp chunk (1/thread), Gt chunks (4/thread)
    const int zs = t >> 7, zq = (t >> 5) & 3, zp = t & 31;
    const int qp_g = zp * 64 + zs * 32 + zq * 8;   // + p0*64
    const int qp_l = zp * 72 + zs * 32 + zq * 8;
    int gg[4], gl[4];
#pragma unroll
    for (int r = 0; r < 4; ++r) {
        int idx = r * 256 + t;
        int c = idx & 255, g8 = idx >> 8;
        gg[r] = c * 4096 + g8 * 8;   // + p0
        gl[r] = c * 40 + g8 * 8;
    }

    const f32x4 z4 = {0.f, 0.f, 0.f, 0.f};
    f32x4 acc[4][4];
#pragma unroll
    for (int a = 0; a < 4; ++a)
#pragma unroll
        for (int b = 0; b < 4; ++b) acc[a][b] = z4;

    // prologue: stage step 0
    {
        uint4 vq = *(const uint4*)(Qn + qp_g);
        *(uint4*)&sQp[0][qp_l] = vq;
#pragma unroll
        for (int r = 0; r < 4; ++r) {
            uint4 v = *(const uint4*)(Gtn + gg[r]);
            *(uint4*)&sGt[0][gl[r]] = v;
        }
    }
    __syncthreads();

#pragma unroll 1
    for (int i = 0; i < 128; ++i) {
        const int b = i & 1;
        uint4 vq, vg0, vg1, vg2, vg3;
        const bool pf = (i + 1 < 128);
        if (pf) {
            const int p0n = (i + 1) * 32;
            vq  = *(const uint4*)(Qn + p0n * 64 + qp_g);
            vg0 = *(const uint4*)(Gtn + p0n + gg[0]);
            vg1 = *(const uint4*)(Gtn + p0n + gg[1]);
            vg2 = *(const uint4*)(Gtn + p0n + gg[2]);
            vg3 = *(const uint4*)(Gtn + p0n + gg[3]);
        }
        // ---- S phase: wave strip w computes P rows [w*16, w*16+16) ----
        {
            const u16* qp = sQp[b];
#pragma unroll
            for (int nt = 0; nt < 2; ++nt) {
                const u16* base = qp + (nt * 16 + lane16) * 72 + quad * 8;
                f16x8 b0 = ldg8h(base);
                f16x8 b1 = ldg8h(base + 32);
                f32x4 z = z4;
                z = mfma_h(aq0, b0, z);
                z = mfma_h(aq1, b1, z);
                const int qrow = w * 16 + quad * 4;
#pragma unroll
                for (int r = 0; r < 4; ++r)
                    sP[(qrow + r) * 40 + nt * 16 + lane16] = f2bf(__expf(z[r]));
            }
        }
        __syncthreads();
        // ---- PV phase: wave owns channel slice [w*64, w*64+64) ----
        {
            bf16x8 af0 = ldg8b(sP + (0 * 16 + lane16) * 40 + quad * 8);
            bf16x8 af1 = ldg8b(sP + (1 * 16 + lane16) * 40 + quad * 8);
            bf16x8 af2 = ldg8b(sP + (2 * 16 + lane16) * 40 + quad * 8);
            bf16x8 af3 = ldg8b(sP + (3 * 16 + lane16) * 40 + quad * 8);
            const u16* gtb = sGt[b] + (w * 64 + lane16) * 40 + quad * 8;
#pragma unroll
            for (int nt = 0; nt < 4; ++nt) {
                bf16x8 bb = ldg8b(gtb + nt * 16 * 40);
                acc[0][nt] = mfma_bf(af0, bb, acc[0][nt]);
                acc[1][nt] = mfma_bf(af1, bb, acc[1][nt]);
                acc[2][nt] = mfma_bf(af2, bb, acc[2][nt]);
                acc[3][nt] = mfma_bf(af3, bb, acc[3][nt]);
            }
        }
        if (pf) {
            const int nb = 1 - b;
            *(uint4*)&sQp[nb][qp_l] = vq;
            *(uint4*)&sGt[nb][gl[0]] = vg0;
            *(uint4*)&sGt[nb][gl[1]] = vg1;
            *(uint4*)&sGt[nb][gl[2]] = vg2;
            *(uint4*)&sGt[nb][gl[3]] = vg3;
        }
        __syncthreads();
    }

    // ---- epilogue: replicate the reference's reshape scramble ----
    // out pixel = ch*16 + (qb>>2), out channel = (qb&3)*64 + q_local
    const int tb = qb >> 2;
    const int cb = (qb & 3) * 64;
    const float* maskn = mask + n * 4096;
    const float* refn = ref + (size_t)n * 4096 * 256;
    float* outn = out + (size_t)n * 4096 * 512;
#pragma unroll
    for (int nt = 0; nt < 4; ++nt) {
        const int ch = w * 64 + nt * 16 + lane16;
        const int pixel = ch * 16 + tb;
        const float m = maskn[pixel];
#pragma unroll
        for (int mt = 0; mt < 4; ++mt) {
            const int c4 = cb + mt * 16 + quad * 4;
            float4 r4 = *(const float4*)(refn + (size_t)pixel * 256 + c4);
            float a0 = acc[mt][nt][0], a1 = acc[mt][nt][1];
            float a2 = acc[mt][nt][2], a3 = acc[mt][nt][3];
            float4 a4 = {a0, a1, a2, a3};
            float4 bl4 = {m * a0 + (1.f - m) * r4.x,
                          m * a1 + (1.f - m) * r4.y,
                          m * a2 + (1.f - m) * r4.z,
                          m * a3 + (1.f - m) * r4.w};
            *(float4*)(outn + (size_t)pixel * 512 + 256 + c4) = a4;   // src_att
            *(float4*)(outn + (size_t)pixel * 512 + c4) = bl4;        // ex_guide_flow
        }
    }
}

extern "C" void kernel_launch(void* const* d_in, const int* in_sizes, int n_in,
                              void* d_out, int out_size, void* d_ws, size_t ws_size,
                              hipStream_t stream) {
    const float* mask = (const float*)d_in[0];   // (8,64,64) f32
    const float* F    = (const float*)d_in[1];   // (8,64,64,256) f32
    const float* ref  = (const float*)d_in[2];   // (8,64,64,256) f32
    const float* Wq   = (const float*)d_in[3];   // (256,64) f32
    float* out = (float*)d_out;                  // (8,64,64,512) f32
    char* ws = (char*)d_ws;

    u16*   Wthi = (u16*)ws;                                     // 32 KB
    u16*   Wtlo = (u16*)(ws + 32768);                           // 32 KB
    u16*   Qh   = (u16*)(ws + 65536);                           // 4 MB (fp16)
    float* invl = (float*)(ws + 65536 + 4194304);               // 128 KB
    u16*   Gt   = (u16*)(ws + 65536 + 4194304 + 131072);        // 16 MB (bf16)

    k0_wt   <<<64,   256, 0, stream>>>(Wq, Wthi, Wtlo);
    k1_query<<<512,  256, 0, stream>>>(F, Wthi, Wtlo, Qh);
    k2_suminv<<<512, 256, 0, stream>>>(Qh, invl);
    k3_gt   <<<2048, 256, 0, stream>>>(F, invl, Gt);
    k4_attn <<<512,  256, 0, stream>>>(Qh, Gt, mask, ref, out);
}

// Round 3
// 272.093 us; speedup vs baseline: 1.3088x; 1.3088x over previous
//
#include <hip/hip_runtime.h>

typedef unsigned short u16;
typedef unsigned int u32;
typedef __attribute__((ext_vector_type(8))) __bf16 bf16x8;
typedef __attribute__((ext_vector_type(8))) _Float16 f16x8;
typedef __attribute__((ext_vector_type(4))) float f32x4;

// ---------- helpers ----------
__device__ __forceinline__ float b2f(u16 b) {
    union { u32 u; float f; } v; v.u = ((u32)b) << 16; return v.f;
}
__device__ __forceinline__ u16 f2bf(float f) {
    union { float f; u32 u; } v; v.f = f;
    u32 u = v.u;
    return (u16)((u + 0x7fffu + ((u >> 16) & 1u)) >> 16);  // RNE
}
__device__ __forceinline__ u16 f2h(float f) {
    _Float16 h = (_Float16)f;
    return __builtin_bit_cast(u16, h);
}
__device__ __forceinline__ bf16x8 ldg8b(const u16* p) {
    uint4 v = *(const uint4*)p;
    return __builtin_bit_cast(bf16x8, v);
}
__device__ __forceinline__ f16x8 ldg8h(const u16* p) {
    uint4 v = *(const uint4*)p;
    return __builtin_bit_cast(f16x8, v);
}
__device__ __forceinline__ f32x4 mfma_bf(bf16x8 a, bf16x8 b, f32x4 c) {
    return __builtin_amdgcn_mfma_f32_16x16x32_bf16(a, b, c, 0, 0, 0);
}
__device__ __forceinline__ f32x4 mfma_h(f16x8 a, f16x8 b, f32x4 c) {
    return __builtin_amdgcn_mfma_f32_16x16x32_f16(a, b, c, 0, 0, 0);
}
// async global->LDS: lds dest = wave-uniform base + lane*16
__device__ __forceinline__ void gld16(const u16* g, u16* l) {
    __builtin_amdgcn_global_load_lds(
        (const __attribute__((address_space(1))) u32*)g,
        (__attribute__((address_space(3))) u32*)l, 16, 0, 0);
}

// Q global layout: per batch, row p (4096): 64 fp16, elem slot = d ^ ((p&7)*8)
// Gt global layout: per (n, step s of 64 p): 16384 elems: ch*64 + ((pp&~7)^((ch&7)*8)) + (pp&7)

// ---------- K0: hi/lo bf16 split of W, transposed: Wt[d][c] ----------
__global__ void k0_wt(const float* __restrict__ Wq,
                      u16* __restrict__ Wthi, u16* __restrict__ Wtlo) {
    int idx = blockIdx.x * 256 + threadIdx.x;   // 64 blocks -> 16384
    int c = idx >> 6, d = idx & 63;
    float w = Wq[idx];
    u16 hi = f2bf(w);
    float rem = w - b2f(hi);
    Wthi[d * 256 + c] = hi;
    Wtlo[d * 256 + c] = f2bf(rem);
}

// ---------- K1: Q = F*W (hi/lo split MFMA), fp16 out, XOR-swizzled rows ----------
__global__ __launch_bounds__(256) void k1_query(
    const float* __restrict__ F, const u16* __restrict__ Wthi,
    const u16* __restrict__ Wtlo, u16* __restrict__ Qh) {
    const int t = threadIdx.x;
    const int w = t >> 6, L = t & 63, lane16 = L & 15, quad = L >> 4;
    const int R0 = blockIdx.x * 64;
    const int row = R0 + w * 16 + lane16;
    const f32x4 z4 = {0.f, 0.f, 0.f, 0.f};
    f32x4 acc[4] = {z4, z4, z4, z4};
    union U8 { bf16x8 v; u16 s[8]; };
#pragma unroll
    for (int ks = 0; ks < 8; ++ks) {
        const float* fp = F + (size_t)row * 256 + ks * 32 + quad * 8;
        float4 x0 = *(const float4*)fp;
        float4 x1 = *(const float4*)(fp + 4);
        float xs[8] = {x0.x, x0.y, x0.z, x0.w, x1.x, x1.y, x1.z, x1.w};
        U8 ahi, alo;
#pragma unroll
        for (int j = 0; j < 8; ++j) {
            u16 h = f2bf(xs[j]);
            ahi.s[j] = h;
            alo.s[j] = f2bf(xs[j] - b2f(h));
        }
#pragma unroll
        for (int nt = 0; nt < 4; ++nt) {
            const int off = (nt * 16 + lane16) * 256 + ks * 32 + quad * 8;
            bf16x8 bh = ldg8b(Wthi + off);
            bf16x8 bl = ldg8b(Wtlo + off);
            acc[nt] = mfma_bf(ahi.v, bh, acc[nt]);
            acc[nt] = mfma_bf(alo.v, bh, acc[nt]);
            acc[nt] = mfma_bf(ahi.v, bl, acc[nt]);
        }
    }
    const int orow = R0 + w * 16 + quad * 4;
#pragma unroll
    for (int nt = 0; nt < 4; ++nt) {
        const int d = nt * 16 + lane16;
#pragma unroll
        for (int r = 0; r < 4; ++r) {
            const int p = orow + r;
            Qh[(size_t)p * 64 + (d ^ ((p & 7) << 3))] = f2h(acc[nt][r]);
        }
    }
}

// ---------- K2: inv_l[p] = 1 / sum_q exp(Q_p . Q_q), p-tile 32, grid 1024 ----------
__global__ __launch_bounds__(256) void k2_suminv(
    const u16* __restrict__ Q, float* __restrict__ inv_l) {
    const int t = threadIdx.x;
    const int w = t >> 6, L = t & 63, lane16 = L & 15, quad = L >> 4, l7 = lane16 & 7;
    const int bx = blockIdx.x;
    const int n = bx & 7, pb = bx >> 3;   // batch-per-XCD swizzle
    const int P0 = pb * 32;
    const u16* Qn = Q + (size_t)n * 4096 * 64;

    f16x8 ap[2][2];
#pragma unroll
    for (int st = 0; st < 2; ++st) {
        const int row = P0 + st * 16 + lane16;
        ap[st][0] = ldg8h(Qn + row * 64 + ((quad * 8) ^ (l7 * 8)));
        ap[st][1] = ldg8h(Qn + row * 64 + ((32 + quad * 8) ^ (l7 * 8)));
    }
    float sums[2][4];
#pragma unroll
    for (int st = 0; st < 2; ++st)
#pragma unroll
        for (int r = 0; r < 4; ++r) sums[st][r] = 0.f;

    const f32x4 z4 = {0.f, 0.f, 0.f, 0.f};
    for (int s = 0; s < 32; ++s) {
#pragma unroll
        for (int nt = 0; nt < 2; ++nt) {
            const int qr = w * 1024 + s * 32 + nt * 16 + lane16;
            f16x8 b0 = ldg8h(Qn + qr * 64 + ((quad * 8) ^ (l7 * 8)));
            f16x8 b1 = ldg8h(Qn + qr * 64 + ((32 + quad * 8) ^ (l7 * 8)));
#pragma unroll
            for (int st = 0; st < 2; ++st) {
                f32x4 z = z4;
                z = mfma_h(ap[st][0], b0, z);
                z = mfma_h(ap[st][1], b1, z);
                sums[st][0] += __expf(z[0]);
                sums[st][1] += __expf(z[1]);
                sums[st][2] += __expf(z[2]);
                sums[st][3] += __expf(z[3]);
            }
        }
    }
    __shared__ float red[4][32];
#pragma unroll
    for (int st = 0; st < 2; ++st)
#pragma unroll
        for (int r = 0; r < 4; ++r) {
            float v = sums[st][r];
            v += __shfl_xor(v, 1);
            v += __shfl_xor(v, 2);
            v += __shfl_xor(v, 4);
            v += __shfl_xor(v, 8);
            if (lane16 == 0) red[w][st * 16 + quad * 4 + r] = v;
        }
    __syncthreads();
    if (t < 32) {
        float tot = red[0][t] + red[1][t] + red[2][t] + red[3][t];
        inv_l[n * 4096 + P0 + t] = 1.0f / tot;
    }
}

// ---------- K3: Gt_sw[n][s][ch][p-swizzled] = bf16(F[n][p][ch]) ----------
__global__ __launch_bounds__(256) void k3_gt(
    const float* __restrict__ F, u16* __restrict__ Gt) {
    const int t = threadIdx.x;
    const int bx = blockIdx.x;                  // 512 = 8 n * 64 s
    const int n = bx >> 6, s = bx & 63;
    const int p0 = s * 64;
    __shared__ float tile[64][65];
    const float* Fn = F + (size_t)n * 4096 * 256;
    u16* Gn = Gt + (size_t)(n * 64 + s) * 16384;
#pragma unroll 1
    for (int ct = 0; ct < 4; ++ct) {
        const int c0 = ct * 64;
        if (ct > 0) __syncthreads();
#pragma unroll
        for (int k = 0; k < 16; ++k) {
            int idx = k * 256 + t;
            int r = idx >> 6, cc = idx & 63;
            tile[r][cc] = Fn[(size_t)(p0 + r) * 256 + c0 + cc];
        }
        __syncthreads();
#pragma unroll
        for (int k = 0; k < 2; ++k) {
            int u = k * 256 + t;
            int cc = u & 63, S = u >> 6;          // S in [0,8)
            int G = S ^ (cc & 7);
            u16 v[8];
#pragma unroll
            for (int j = 0; j < 8; ++j) v[j] = f2bf(tile[G * 8 + j][cc]);
            uint4 pk;
            pk.x = (u32)v[0] | ((u32)v[1] << 16);
            pk.y = (u32)v[2] | ((u32)v[3] << 16);
            pk.z = (u32)v[4] | ((u32)v[5] << 16);
            pk.w = (u32)v[6] | ((u32)v[7] << 16);
            *(uint4*)&Gn[(c0 + cc) * 64 + S * 8] = pk;
        }
    }
}

// ---------- K4: out tile 64q x 256ch, p-step 64, DMA staging, swapped-S ----------
__global__ __launch_bounds__(256, 2) void k4_attn(
    const u16* __restrict__ Q, const u16* __restrict__ Gt,
    const float* __restrict__ invl, const float* __restrict__ mask,
    const float* __restrict__ ref, float* __restrict__ out) {
    const int t = threadIdx.x;
    const int w = t >> 6, L = t & 63, lane16 = L & 15, quad = L >> 4, l7 = lane16 & 7;
    const int bx = blockIdx.x;
    const int n = bx & 7, qb = bx >> 3;   // batch-per-XCD swizzle
    const int q0 = qb << 6;

    __shared__ u16 sGt[16384];   // 32 KB: step's 256ch x 64p (swizzled)
    __shared__ u16 sQp[4096];    // 8 KB: step's 64 p-rows of Q (swizzled)
    __shared__ u16 sP[4096];     // 8 KB: P' 64q x 64p (swizzled)

    const u16* Qn = Q + (size_t)n * 4096 * 64;
    const u16* Gtn = Gt + (size_t)n * 64 * 16384;
    const float* iln = invl + n * 4096;

    // invariant B-frags: this block's 64 q-rows of Q
    f16x8 bq[4][2];
#pragma unroll
    for (int qt = 0; qt < 4; ++qt) {
        const int row = q0 + qt * 16 + lane16;
        bq[qt][0] = ldg8h(Qn + row * 64 + ((quad * 8) ^ (l7 * 8)));
        bq[qt][1] = ldg8h(Qn + row * 64 + ((32 + quad * 8) ^ (l7 * 8)));
    }

    // loop-invariant LDS addresses
    const int pl = w * 16 + lane16;                       // S-phase A rows (p-strip w)
    const int sA0 = pl * 64 + ((quad * 8) ^ (l7 * 8));
    const int sA1 = pl * 64 + ((32 + quad * 8) ^ (l7 * 8));
    int wrP[4];
#pragma unroll
    for (int qt = 0; qt < 4; ++qt)
        wrP[qt] = (qt * 16 + lane16) * 64 +
                  ((w * 16 + 8 * (quad >> 1)) ^ (l7 * 8)) + 4 * (quad & 1);
    const int dl = L * 8;                                  // DMA lane offset (elems)

    const f32x4 z4 = {0.f, 0.f, 0.f, 0.f};
    f32x4 acc[4][4];
#pragma unroll
    for (int a = 0; a < 4; ++a)
#pragma unroll
        for (int b = 0; b < 4; ++b) acc[a][b] = z4;

    // prologue: DMA sQp for step 0
#pragma unroll
    for (int j = 0; j < 2; ++j) {
        const int c = w * 2 + j;
        gld16(Qn + c * 512 + dl, &sQp[c * 512]);
    }
    __syncthreads();

#pragma unroll 1
    for (int i = 0; i < 64; ++i) {
        // DMA sGt for step i (PV(i-1) reads done before last barrier)
#pragma unroll
        for (int j = 0; j < 8; ++j) {
            const int c = w * 8 + j;
            gld16(Gtn + (size_t)i * 16384 + c * 512 + dl, &sGt[c * 512]);
        }
        // ---- S phase: wave w computes P' rows p-strip w, all 64 q ----
        {
            f16x8 a0 = ldg8h(&sQp[sA0]);
            f16x8 a1 = ldg8h(&sQp[sA1]);
            float4 il4 = *(const float4*)(iln + i * 64 + w * 16 + quad * 4);
#pragma unroll
            for (int qt = 0; qt < 4; ++qt) {
                f32x4 z = z4;
                z = mfma_h(a0, bq[qt][0], z);
                z = mfma_h(a1, bq[qt][1], z);
                ushort4 pk;
                pk.x = f2bf(__expf(z[0]) * il4.x);
                pk.y = f2bf(__expf(z[1]) * il4.y);
                pk.z = f2bf(__expf(z[2]) * il4.z);
                pk.w = f2bf(__expf(z[3]) * il4.w);
                *(ushort4*)&sP[wrP[qt]] = pk;
            }
        }
        __syncthreads();   // drains sGt DMA; sP visible
        // DMA sQp for step i+1 (S(i) reads done)
        if (i + 1 < 64) {
#pragma unroll
            for (int j = 0; j < 2; ++j) {
                const int c = w * 2 + j;
                gld16(Qn + (size_t)(i + 1) * 4096 + c * 512 + dl, &sQp[c * 512]);
            }
        }
        // ---- PV phase: wave owns ch slice [w*64, w*64+64) ----
#pragma unroll
        for (int h = 0; h < 2; ++h) {
            bf16x8 af[4], bb[4];
#pragma unroll
            for (int m = 0; m < 4; ++m)
                af[m] = ldg8b(&sP[(m * 16 + lane16) * 64 + ((h * 32 + quad * 8) ^ (l7 * 8))]);
#pragma unroll
            for (int nt = 0; nt < 4; ++nt)
                bb[nt] = ldg8b(&sGt[(w * 64 + nt * 16 + lane16) * 64 +
                                    ((h * 32 + quad * 8) ^ (l7 * 8))]);
#pragma unroll
            for (int nt = 0; nt < 4; ++nt)
#pragma unroll
                for (int m = 0; m < 4; ++m)
                    acc[m][nt] = mfma_bf(af[m], bb[nt], acc[m][nt]);
        }
        __syncthreads();   // drains sQp DMA; protects sP/sGt rewrite
    }

    // ---- epilogue: replicate the reference's reshape scramble ----
    // out pixel = ch*16 + (qb>>2), out channel = (qb&3)*64 + q_local
    const int tb = qb >> 2;
    const int cb = (qb & 3) * 64;
    const float* maskn = mask + n * 4096;
    const float* refn = ref + (size_t)n * 4096 * 256;
    float* outn = out + (size_t)n * 4096 * 512;
#pragma unroll
    for (int nt = 0; nt < 4; ++nt) {
        const int ch = w * 64 + nt * 16 + lane16;
        const int pixel = ch * 16 + tb;
        const float m = maskn[pixel];
#pragma unroll
        for (int mt = 0; mt < 4; ++mt) {
            const int c4 = cb + mt * 16 + quad * 4;
            float4 r4 = *(const float4*)(refn + (size_t)pixel * 256 + c4);
            float a0 = acc[mt][nt][0], a1 = acc[mt][nt][1];
            float a2 = acc[mt][nt][2], a3 = acc[mt][nt][3];
            float4 a4 = {a0, a1, a2, a3};
            float4 bl4 = {m * a0 + (1.f - m) * r4.x,
                          m * a1 + (1.f - m) * r4.y,
                          m * a2 + (1.f - m) * r4.z,
                          m * a3 + (1.f - m) * r4.w};
            *(float4*)(outn + (size_t)pixel * 512 + 256 + c4) = a4;   // src_att
            *(float4*)(outn + (size_t)pixel * 512 + c4) = bl4;        // ex_guide_flow
        }
    }
}

extern "C" void kernel_launch(void* const* d_in, const int* in_sizes, int n_in,
                              void* d_out, int out_size, void* d_ws, size_t ws_size,
                              hipStream_t stream) {
    const float* mask = (const float*)d_in[0];   // (8,64,64) f32
    const float* F    = (const float*)d_in[1];   // (8,64,64,256) f32
    const float* ref  = (const float*)d_in[2];   // (8,64,64,256) f32
    const float* Wq   = (const float*)d_in[3];   // (256,64) f32
    float* out = (float*)d_out;                  // (8,64,64,512) f32
    char* ws = (char*)d_ws;

    u16*   Wthi = (u16*)ws;                                     // 32 KB
    u16*   Wtlo = (u16*)(ws + 32768);                           // 32 KB
    u16*   Qh   = (u16*)(ws + 65536);                           // 4 MB (fp16, swizzled)
    float* invl = (float*)(ws + 65536 + 4194304);               // 128 KB
    u16*   Gt   = (u16*)(ws + 65536 + 4194304 + 131072);        // 16 MB (bf16, swizzled)

    k0_wt    <<<64,   256, 0, stream>>>(Wq, Wthi, Wtlo);
    k1_query <<<512,  256, 0, stream>>>(F, Wthi, Wtlo, Qh);
    k2_suminv<<<1024, 256, 0, stream>>>(Qh, invl);
    k3_gt    <<<512,  256, 0, stream>>>(F, Gt);
    k4_attn  <<<512,  256, 0, stream>>>(Qh, Gt, invl, mask, ref, out);
}